// Round 9
// baseline (404.166 us; speedup 1.0000x reference)
//
#include <hip/hip_runtime.h>

// GraphAE: 2x GCNConv encoder + 2-layer MLP decoder.
// N=50000, IN=128, HID=256, LAT=64, E=800000. fp32 in/out.
//
// R9 changes vs R8:
//  - GEMMs: grid.y=1; the 4 waves of each block SPLIT the output columns
//    (wave wid owns NJ 16-col tiles), sharing the block's MI row-tiles.
//    A is read from HBM exactly once per GEMM (was 2-4x; cross-wave A reuse
//    is served by L1/L2 on the same CU).
//  - prescale folded into scan3 (one dispatch fewer).
// (R8: MFMA-frag-tiled hi/lo bf16 planes for all GEMM operands ->
//  LDS-free barrier-free bf16x3 GEMMs with 1KB-contiguous frag loads.)

#define IN_CH  128
#define HIDDEN 256
#define LATENT 64

typedef unsigned short u16;
typedef unsigned int u32;
typedef __bf16 bf16x8 __attribute__((ext_vector_type(8)));
typedef float f32x4 __attribute__((ext_vector_type(4)));

static __device__ __forceinline__ float4 ld4(const float* p) {
    return *reinterpret_cast<const float4*>(p);
}
static __device__ __forceinline__ void st4(float* p, float4 v) {
    *reinterpret_cast<float4*>(p) = v;
}
static __device__ __forceinline__ void acc4(float4& a, float4 v) {
    a.x += v.x; a.y += v.y; a.z += v.z; a.w += v.w;
}

// truncating hi/lo split: hi = top16(v); lo = top16(v - hi). v-hi exact.
static __device__ __forceinline__ void split_bf16(float v, u16& hi, u16& lo) {
    u32 b = __float_as_uint(v);
    hi = (u16)(b >> 16);
    float hf = __uint_as_float(b & 0xFFFF0000u);
    lo = (u16)(__float_as_uint(v - hf) >> 16);
}

// tiled-layout offset (elements). K multiple of 8; row tiles of 16.
static __device__ __forceinline__ long tix(int row, int k, int K) {
    return ((long)(row >> 4) * (K >> 3) + (k >> 3)) * 128 + ((row & 15) << 3) + (k & 7);
}

// ---------------- graph structure kernels ----------------

__global__ void hist_kernel(const int* __restrict__ ei, int E, int* __restrict__ counts) {
    int e = blockIdx.x * 256 + threadIdx.x;
    if (e < E) atomicAdd(&counts[ei[E + e]], 1);
}

// scan1 also emits dinv[i] = rsqrt(counts[i]+1)
__global__ void scan1_kernel(const int* __restrict__ counts, int* __restrict__ rowptr,
                             int* __restrict__ blocksums, float* __restrict__ dinv, int N) {
    __shared__ int sh[256];
    int tid = threadIdx.x;
    int i = blockIdx.x * 256 + tid;
    int v = (i < N) ? counts[i] : 0;
    if (i < N) dinv[i] = rsqrtf((float)v + 1.0f);
    sh[tid] = v;
    __syncthreads();
    for (int off = 1; off < 256; off <<= 1) {
        int t = (tid >= off) ? sh[tid - off] : 0;
        __syncthreads();
        sh[tid] += t;
        __syncthreads();
    }
    if (i < N) rowptr[i] = sh[tid] - v;
    if (tid == 255) blocksums[blockIdx.x] = sh[255];
}

__global__ void scan2_kernel(const int* __restrict__ blocksums, int* __restrict__ blockoffs,
                             int* __restrict__ rowptr, int nblk, int N) {
    __shared__ int sh[256];
    int tid = threadIdx.x;
    int v = (tid < nblk) ? blocksums[tid] : 0;
    sh[tid] = v;
    __syncthreads();
    for (int off = 1; off < 256; off <<= 1) {
        int t = (tid >= off) ? sh[tid - off] : 0;
        __syncthreads();
        sh[tid] += t;
        __syncthreads();
    }
    if (tid < nblk) blockoffs[tid] = sh[tid] - v;
    if (tid == nblk - 1) rowptr[N] = sh[tid];
}

// scan3 (finalize rowptr, init nxt) + prescale xs = dinv*x, fused.
// grid covers total4 = N*32 threads; first N also do scan3 duty.
__global__ void scan3_prescale_kernel(
    int* __restrict__ rowptr, const int* __restrict__ blockoffs, int* __restrict__ next,
    const float* __restrict__ x, const float* __restrict__ dinv, float* __restrict__ xs,
    int N, int total4) {
    int i = blockIdx.x * 256 + threadIdx.x;
    if (i < N) {
        int r = rowptr[i] + blockoffs[i >> 8];
        rowptr[i] = r;
        next[i] = r;
    }
    if (i < total4) {
        float s = dinv[i >> 5];
        float4 v = ld4(&x[(long)i * 4]);
        v.x *= s; v.y *= s; v.z *= s; v.w *= s;
        st4(&xs[(long)i * 4], v);
    }
}

__global__ void fill_kernel(const int* __restrict__ ei, int E,
                            int* __restrict__ next, int* __restrict__ col) {
    int e = blockIdx.x * 256 + threadIdx.x;
    if (e < E) {
        int s = ei[e];
        int d = ei[E + e];
        int pos = atomicAdd(&next[d], 1);
        col[pos] = s;
    }
}

// All four weights: W[K,N] fp32 -> transposed TILED hi/lo planes (rows=n).
__global__ void wsplit_all(
    const float* __restrict__ W1, const float* __restrict__ W2,
    const float* __restrict__ Wd1, const float* __restrict__ Wd2,
    u16* __restrict__ w1h, u16* __restrict__ w1l, u16* __restrict__ w2h, u16* __restrict__ w2l,
    u16* __restrict__ wd1h, u16* __restrict__ wd1l, u16* __restrict__ wd2h, u16* __restrict__ wd2l) {
    int idx = blockIdx.x * 256 + threadIdx.x;
    const float* W; u16 *H, *L; int K, N, base;
    if (idx < 32768)      { W = W1;  H = w1h;  L = w1l;  K = 128; N = 256; base = idx; }
    else if (idx < 49152) { W = W2;  H = w2h;  L = w2l;  K = 256; N = 64;  base = idx - 32768; }
    else if (idx < 65536) { W = Wd1; H = wd1h; L = wd1l; K = 64;  N = 256; base = idx - 49152; }
    else if (idx < 98304) { W = Wd2; H = wd2h; L = wd2l; K = 256; N = 128; base = idx - 65536; }
    else return;
    int k = base / N, n = base % N;
    u16 h, l;
    split_bf16(W[base], h, l);
    long o = tix(n, k, K);
    H[o] = h;
    L[o] = l;
}

// ---------------- tiled-layout LDS-free bf16x3 GEMM (wave-column split) ----------------
// Block = 4 waves sharing MI row-tiles; wave wid owns cols [wid*NJ*16, +NJ*16).
// NOUT must equal 4*NJ*16. grid = ceil(M/(MI*16)) blocks. A read once from HBM
// per GEMM (cross-wave A reuse hits L1/L2 on the same CU).

template <int KT, int NOUT, int MI, int NJ,
          bool SPLIT_OUT, bool ADD_BIAS, bool RELU, bool SCALE_DINV>
__global__ __launch_bounds__(256) void gemm_tiled(
    const u16* __restrict__ Ahi, const u16* __restrict__ Alo,
    const u16* __restrict__ Bthi, const u16* __restrict__ Btlo,
    float* __restrict__ Cf, u16* __restrict__ Chi, u16* __restrict__ Clo,
    const float* __restrict__ dinv, const float* __restrict__ bias, int M) {
    static_assert(NOUT == 4 * NJ * 16, "column cover");
    constexpr int KC = KT / 32;
    constexpr int KB = KT >> 3;
    const int tid = threadIdx.x;
    const int wid = tid >> 6, lane = tid & 63, quad = lane >> 4, lm = lane & 15;
    const int rt0 = blockIdx.x * MI;               // block's first row tile
    const int n0 = wid * (NJ * 16);
    const int nt0 = n0 >> 4;
    const int last_rt = (M >> 4) - 1;              // M % 16 == 0

    f32x4 acc[MI][NJ];
#pragma unroll
    for (int i = 0; i < MI; i++)
#pragma unroll
        for (int j = 0; j < NJ; j++) acc[i][j] = (f32x4){0.f, 0.f, 0.f, 0.f};

#pragma unroll 4
    for (int kc = 0; kc < KC; kc++) {
        const int kb = kc * 4 + quad;
        bf16x8 ah[MI], al[MI], bh[NJ], bl[NJ];
#pragma unroll
        for (int i = 0; i < MI; i++) {
            int rt = rt0 + i; rt = rt <= last_rt ? rt : last_rt;
            long o = ((long)rt * KB + kb) * 128 + lm * 8;
            ah[i] = *(const bf16x8*)&Ahi[o];
            al[i] = *(const bf16x8*)&Alo[o];
        }
#pragma unroll
        for (int j = 0; j < NJ; j++) {
            long o = ((long)(nt0 + j) * KB + kb) * 128 + lm * 8;
            bh[j] = *(const bf16x8*)&Bthi[o];
            bl[j] = *(const bf16x8*)&Btlo[o];
        }
#pragma unroll
        for (int i = 0; i < MI; i++)
#pragma unroll
            for (int j = 0; j < NJ; j++) {
                acc[i][j] = __builtin_amdgcn_mfma_f32_16x16x32_bf16(ah[i], bh[j], acc[i][j], 0, 0, 0);
                acc[i][j] = __builtin_amdgcn_mfma_f32_16x16x32_bf16(ah[i], bl[j], acc[i][j], 0, 0, 0);
                acc[i][j] = __builtin_amdgcn_mfma_f32_16x16x32_bf16(al[i], bh[j], acc[i][j], 0, 0, 0);
            }
    }

    // epilogue: C/D mapping col=lane&15, row=quad*4+reg
#pragma unroll
    for (int i = 0; i < MI; i++)
#pragma unroll
        for (int j = 0; j < NJ; j++) {
            int coln = n0 + j * 16 + lm;
            float bi = ADD_BIAS ? bias[coln] : 0.0f;
#pragma unroll
            for (int r = 0; r < 4; r++) {
                int row = (rt0 + i) * 16 + quad * 4 + r;
                if (row < M) {
                    float v = acc[i][j][r];
                    if (SCALE_DINV) v *= dinv[row];
                    if (ADD_BIAS) v += bi;
                    if (RELU) v = fmaxf(v, 0.f);
                    if (SPLIT_OUT) {
                        u16 h, l;
                        split_bf16(v, h, l);
                        long o = tix(row, coln, NOUT);
                        Chi[o] = h;
                        Clo[o] = l;
                    } else {
                        Cf[(long)row * NOUT + coln] = v;
                    }
                }
            }
        }
}

// ---------------- aggregation kernels ----------------

// AGGX: xa[i] = dinv[i]*(xs[i] + sum_in xs[s]); writes TILED hi/lo planes.
__global__ __launch_bounds__(256) void aggx_kernel(
    const float* __restrict__ xs, const int* __restrict__ rowptr, const int* __restrict__ col,
    const float* __restrict__ dinv, u16* __restrict__ xahi, u16* __restrict__ xalo, int N) {
    int wid = threadIdx.x >> 6;
    int lane = threadIdx.x & 63;
    int node = blockIdx.x * 4 + wid;
    if (node >= N) return;
    int slot = lane >> 5;
    int c = (lane & 31) * 4;

    float4 a0 = make_float4(0.f, 0.f, 0.f, 0.f);
    float4 a1 = a0, a2 = a0, a3 = a0;
    if (slot == 0) a0 = ld4(&xs[(long)node * 128 + c]);

    int beg = rowptr[node];
    int end = rowptr[node + 1];
    for (int cb = beg; cb < end; cb += 64) {
        int cnt = min(64, end - cb);
        int cv = (lane < cnt) ? col[cb + lane] : 0;
        int full = cnt >> 1;
        int trips = (cnt + 1) >> 1;
        int t = 0;
        for (; t + 4 <= full; t += 4) {
            int j = slot + 2 * t;
            int s0 = __shfl(cv, j);
            int s1 = __shfl(cv, j + 2);
            int s2 = __shfl(cv, j + 4);
            int s3 = __shfl(cv, j + 6);
            float4 v0 = ld4(&xs[(long)s0 * 128 + c]);
            float4 v1 = ld4(&xs[(long)s1 * 128 + c]);
            float4 v2 = ld4(&xs[(long)s2 * 128 + c]);
            float4 v3 = ld4(&xs[(long)s3 * 128 + c]);
            acc4(a0, v0); acc4(a1, v1); acc4(a2, v2); acc4(a3, v3);
        }
        for (; t < trips; t++) {
            int j = slot + 2 * t;
            bool p = j < cnt;
            int s = __shfl(cv, p ? j : 0);
            if (p) acc4(a0, ld4(&xs[(long)s * 128 + c]));
        }
    }
    acc4(a0, a1); acc4(a2, a3); acc4(a0, a2);
    a0.x += __shfl_xor(a0.x, 32);
    a0.y += __shfl_xor(a0.y, 32);
    a0.z += __shfl_xor(a0.z, 32);
    a0.w += __shfl_xor(a0.w, 32);
    if (slot == 0) {
        float di = dinv[node];
        a0.x *= di; a0.y *= di; a0.z *= di; a0.w *= di;
        ushort4 h, l;
        split_bf16(a0.x, h.x, l.x);
        split_bf16(a0.y, h.y, l.y);
        split_bf16(a0.z, h.z, l.z);
        split_bf16(a0.w, h.w, l.w);
        long o = tix(node, c, 128);
        *(ushort4*)&xahi[o] = h;
        *(ushort4*)&xalo[o] = l;
    }
}

// AGG2: z[i] = dinv[i]*(zs[i] + sum_in zs[s]) + b2; writes TILED hi/lo planes.
__global__ __launch_bounds__(256) void agg64_kernel(
    const float* __restrict__ zs, const int* __restrict__ rowptr, const int* __restrict__ col,
    const float* __restrict__ dinv, const float* __restrict__ bias,
    u16* __restrict__ zhi, u16* __restrict__ zlo, int N) {
    int wid = threadIdx.x >> 6;
    int lane = threadIdx.x & 63;
    int node = blockIdx.x * 4 + wid;
    if (node >= N) return;
    int slot = lane >> 4;
    int c = (lane & 15) * 4;

    float4 a0 = make_float4(0.f, 0.f, 0.f, 0.f);
    float4 a1 = a0;
    if (slot == 0) a0 = ld4(&zs[(long)node * 64 + c]);

    int beg = rowptr[node];
    int end = rowptr[node + 1];
    for (int cb = beg; cb < end; cb += 64) {
        int cnt = min(64, end - cb);
        int cv = (lane < cnt) ? col[cb + lane] : 0;
        int full = cnt >> 2;
        int trips = (cnt + 3) >> 2;
        int t = 0;
        for (; t + 2 <= full; t += 2) {
            int j = slot + 4 * t;
            int s0 = __shfl(cv, j);
            int s1 = __shfl(cv, j + 4);
            float4 v0 = ld4(&zs[(long)s0 * 64 + c]);
            float4 v1 = ld4(&zs[(long)s1 * 64 + c]);
            acc4(a0, v0); acc4(a1, v1);
        }
        for (; t < trips; t++) {
            int j = slot + 4 * t;
            bool p = j < cnt;
            int s = __shfl(cv, p ? j : 0);
            if (p) acc4(a0, ld4(&zs[(long)s * 64 + c]));
        }
    }
    acc4(a0, a1);
    a0.x += __shfl_xor(a0.x, 16); a0.x += __shfl_xor(a0.x, 32);
    a0.y += __shfl_xor(a0.y, 16); a0.y += __shfl_xor(a0.y, 32);
    a0.z += __shfl_xor(a0.z, 16); a0.z += __shfl_xor(a0.z, 32);
    a0.w += __shfl_xor(a0.w, 16); a0.w += __shfl_xor(a0.w, 32);
    if (slot == 0) {
        float di = dinv[node];
        float4 bi = ld4(&bias[c]);
        a0.x = a0.x * di + bi.x;
        a0.y = a0.y * di + bi.y;
        a0.z = a0.z * di + bi.z;
        a0.w = a0.w * di + bi.w;
        ushort4 h, l;
        split_bf16(a0.x, h.x, l.x);
        split_bf16(a0.y, h.y, l.y);
        split_bf16(a0.z, h.z, l.z);
        split_bf16(a0.w, h.w, l.w);
        long o = tix(node, c, 64);
        *(ushort4*)&zhi[o] = h;
        *(ushort4*)&zlo[o] = l;
    }
}

// ---------------- launch ----------------

extern "C" void kernel_launch(void* const* d_in, const int* in_sizes, int n_in,
                              void* d_out, int out_size, void* d_ws, size_t ws_size,
                              hipStream_t stream) {
    const float* x        = (const float*)d_in[0];
    const int* ei         = (const int*)d_in[1];   // int32 (harness integer convention)
    const float* W1       = (const float*)d_in[2];
    const float* b1       = (const float*)d_in[3];
    const float* W2       = (const float*)d_in[4];
    const float* b2       = (const float*)d_in[5];
    const float* Wd1      = (const float*)d_in[6];
    const float* bd1      = (const float*)d_in[7];
    const float* Wd2      = (const float*)d_in[8];
    const float* bd2      = (const float*)d_in[9];
    float* out            = (float*)d_out;

    const int N = in_sizes[0] / IN_CH;   // 50000 (multiple of 16)
    const int E = in_sizes[1] / 2;       // 800000

    char* p = (char*)d_ws;
    auto alloc = [&](size_t bytes) {
        char* r = p;
        p += (bytes + 255) & ~(size_t)255;
        return r;
    };
    int*   counts    = (int*)  alloc((size_t)(N + 1) * 4);
    int*   rowptr    = (int*)  alloc((size_t)(N + 1) * 4);
    int*   nxt       = (int*)  alloc((size_t)N * 4);
    int*   blocksums = (int*)  alloc(256 * 4);
    int*   blockoffs = (int*)  alloc(256 * 4);
    float* dinv      = (float*)alloc((size_t)N * 4);
    int*   col       = (int*)  alloc((size_t)E * 4);
    float* xs        = (float*)alloc((size_t)N * IN_CH * 4);     // reused as d_hi
    u16*   xa2       = (u16*)  alloc((size_t)N * IN_CH * 2 * 2); // xa hi|lo; reused as d_lo
    u16*   out1_hi   = (u16*)  alloc((size_t)N * HIDDEN * 2);
    u16*   out1_lo   = (u16*)  alloc((size_t)N * HIDDEN * 2);
    float* zs        = (float*)alloc((size_t)N * LATENT * 4);
    u16*   z_hi      = (u16*)  alloc((size_t)N * LATENT * 2);
    u16*   z_lo      = (u16*)  alloc((size_t)N * LATENT * 2);
    u16*   w1t_hi    = (u16*)  alloc((size_t)IN_CH * HIDDEN * 2);
    u16*   w1t_lo    = (u16*)  alloc((size_t)IN_CH * HIDDEN * 2);
    u16*   w2t_hi    = (u16*)  alloc((size_t)HIDDEN * LATENT * 2);
    u16*   w2t_lo    = (u16*)  alloc((size_t)HIDDEN * LATENT * 2);
    u16*   wd1t_hi   = (u16*)  alloc((size_t)LATENT * HIDDEN * 2);
    u16*   wd1t_lo   = (u16*)  alloc((size_t)LATENT * HIDDEN * 2);
    u16*   wd2t_hi   = (u16*)  alloc((size_t)HIDDEN * IN_CH * 2);
    u16*   wd2t_lo   = (u16*)  alloc((size_t)HIDDEN * IN_CH * 2);

    u16* xa_hi = xa2;
    u16* xa_lo = xa2 + (size_t)N * IN_CH;
    u16* d_hi = (u16*)xs;   // xs dead after aggx
    u16* d_lo = xa2;        // xa dead after GEMM1

    const int nblk = (N + 255) / 256;
    const int total4 = N * (IN_CH / 4);

    hipMemsetAsync(counts, 0, (size_t)(N + 1) * 4, stream);
    hist_kernel<<<(E + 255) / 256, 256, 0, stream>>>(ei, E, counts);
    scan1_kernel<<<nblk, 256, 0, stream>>>(counts, rowptr, blocksums, dinv, N);
    scan2_kernel<<<1, 256, 0, stream>>>(blocksums, blockoffs, rowptr, nblk, N);
    scan3_prescale_kernel<<<(total4 + 255) / 256, 256, 0, stream>>>(
        rowptr, blockoffs, nxt, x, dinv, xs, N, total4);
    fill_kernel<<<(E + 255) / 256, 256, 0, stream>>>(ei, E, nxt, col);
    wsplit_all<<<384, 256, 0, stream>>>(W1, W2, Wd1, Wd2,
                                        w1t_hi, w1t_lo, w2t_hi, w2t_lo,
                                        wd1t_hi, wd1t_lo, wd2t_hi, wd2t_lo);

    // AGGX: xa = D^-1/2 A^ D^-1/2 X (tiled split out)
    aggx_kernel<<<(N + 3) / 4, 256, 0, stream>>>(xs, rowptr, col, dinv, xa_hi, xa_lo, N);

    const int rblk = (N + 63) / 64;  // 782 (MI=4: 64 rows/block)

    // GEMM1: out1 = relu(xa @ W1 + b1) -> tiled split   [N,128]x[128,256]
    gemm_tiled<128, 256, 4, 4, true, true, true, false><<<rblk, 256, 0, stream>>>(
        xa_hi, xa_lo, w1t_hi, w1t_lo, nullptr, out1_hi, out1_lo, nullptr, b1, N);
    // GEMM2: zs = (out1 @ W2) * dinv[row] -> fp32 row-major   [N,256]x[256,64]
    gemm_tiled<256, 64, 4, 1, false, false, false, true><<<rblk, 256, 0, stream>>>(
        out1_hi, out1_lo, w2t_hi, w2t_lo, zs, nullptr, nullptr, dinv, nullptr, N);
    // AGG2: z = dinv*(sum) + b2 -> tiled split
    agg64_kernel<<<(N + 3) / 4, 256, 0, stream>>>(zs, rowptr, col, dinv, b2, z_hi, z_lo, N);
    // GEMM3: d = relu(z @ Wd1 + bd1) -> tiled split   [N,64]x[64,256]
    gemm_tiled<64, 256, 4, 4, true, true, true, false><<<rblk, 256, 0, stream>>>(
        z_hi, z_lo, wd1t_hi, wd1t_lo, nullptr, d_hi, d_lo, nullptr, bd1, N);
    // GEMM4: out = d @ Wd2 + bd2 -> fp32 row-major   [N,256]x[256,128]
    gemm_tiled<256, 128, 4, 2, false, true, false, false><<<rblk, 256, 0, stream>>>(
        d_hi, d_lo, wd2t_hi, wd2t_lo, out, nullptr, nullptr, nullptr, bd2, N);
}

// Round 10
// 332.360 us; speedup vs baseline: 1.2160x; 1.2160x over previous
//
#include <hip/hip_runtime.h>

// GraphAE: 2x GCNConv encoder + 2-layer MLP decoder.
// N=50000, IN=128, HID=256, LAT=64, E=800000. fp32 in/out.
//
// R10 changes vs R9:
//  - GEMM1+GEMM2 fused (enc_fused): 32-row block computes out1[32,256] =
//    relu(xa@W1+b1) into LDS (frag-tiled hi/lo, 32KB), then zs = (out1@W2)*dinv
//    from LDS. out1 never touches HBM (-77 MB, -1 dispatch).
//  - GEMM3+GEMM4 fused (dec_fused): d[32,256] = relu(z@Wd1+bd1) in LDS, then
//    out = d@Wd2+bd2. d never touches HBM (-102 MB, -1 dispatch).
//    (R7's fusion failed on 66KB LDS + DSTRIDE bank conflicts + scattered
//     frags; fixed by 32KB tiles + frag-tiled LDS + tiled global layouts.)
// (R8: MFMA-frag-tiled hi/lo bf16 planes; LDS-free coalesced frag loads.)

#define IN_CH  128
#define HIDDEN 256
#define LATENT 64

typedef unsigned short u16;
typedef unsigned int u32;
typedef __bf16 bf16x8 __attribute__((ext_vector_type(8)));
typedef float f32x4 __attribute__((ext_vector_type(4)));

static __device__ __forceinline__ float4 ld4(const float* p) {
    return *reinterpret_cast<const float4*>(p);
}
static __device__ __forceinline__ void st4(float* p, float4 v) {
    *reinterpret_cast<float4*>(p) = v;
}
static __device__ __forceinline__ void acc4(float4& a, float4 v) {
    a.x += v.x; a.y += v.y; a.z += v.z; a.w += v.w;
}

// truncating hi/lo split: hi = top16(v); lo = top16(v - hi). v-hi exact.
static __device__ __forceinline__ void split_bf16(float v, u16& hi, u16& lo) {
    u32 b = __float_as_uint(v);
    hi = (u16)(b >> 16);
    float hf = __uint_as_float(b & 0xFFFF0000u);
    lo = (u16)(__float_as_uint(v - hf) >> 16);
}

// tiled-layout offset (elements). K multiple of 8; row tiles of 16.
static __device__ __forceinline__ long tix(int row, int k, int K) {
    return ((long)(row >> 4) * (K >> 3) + (k >> 3)) * 128 + ((row & 15) << 3) + (k & 7);
}

#define MFMA3(ACC, AH, AL, BH, BL)                                             \
    ACC = __builtin_amdgcn_mfma_f32_16x16x32_bf16(AH, BH, ACC, 0, 0, 0);       \
    ACC = __builtin_amdgcn_mfma_f32_16x16x32_bf16(AH, BL, ACC, 0, 0, 0);       \
    ACC = __builtin_amdgcn_mfma_f32_16x16x32_bf16(AL, BH, ACC, 0, 0, 0);

// ---------------- graph structure kernels ----------------

__global__ void hist_kernel(const int* __restrict__ ei, int E, int* __restrict__ counts) {
    int e = blockIdx.x * 256 + threadIdx.x;
    if (e < E) atomicAdd(&counts[ei[E + e]], 1);
}

// scan1 also emits dinv[i] = rsqrt(counts[i]+1)
__global__ void scan1_kernel(const int* __restrict__ counts, int* __restrict__ rowptr,
                             int* __restrict__ blocksums, float* __restrict__ dinv, int N) {
    __shared__ int sh[256];
    int tid = threadIdx.x;
    int i = blockIdx.x * 256 + tid;
    int v = (i < N) ? counts[i] : 0;
    if (i < N) dinv[i] = rsqrtf((float)v + 1.0f);
    sh[tid] = v;
    __syncthreads();
    for (int off = 1; off < 256; off <<= 1) {
        int t = (tid >= off) ? sh[tid - off] : 0;
        __syncthreads();
        sh[tid] += t;
        __syncthreads();
    }
    if (i < N) rowptr[i] = sh[tid] - v;
    if (tid == 255) blocksums[blockIdx.x] = sh[255];
}

__global__ void scan2_kernel(const int* __restrict__ blocksums, int* __restrict__ blockoffs,
                             int* __restrict__ rowptr, int nblk, int N) {
    __shared__ int sh[256];
    int tid = threadIdx.x;
    int v = (tid < nblk) ? blocksums[tid] : 0;
    sh[tid] = v;
    __syncthreads();
    for (int off = 1; off < 256; off <<= 1) {
        int t = (tid >= off) ? sh[tid - off] : 0;
        __syncthreads();
        sh[tid] += t;
        __syncthreads();
    }
    if (tid < nblk) blockoffs[tid] = sh[tid] - v;
    if (tid == nblk - 1) rowptr[N] = sh[tid];
}

// scan3 (finalize rowptr, init nxt) + prescale xs = dinv*x, fused.
__global__ void scan3_prescale_kernel(
    int* __restrict__ rowptr, const int* __restrict__ blockoffs, int* __restrict__ next,
    const float* __restrict__ x, const float* __restrict__ dinv, float* __restrict__ xs,
    int N, int total4) {
    int i = blockIdx.x * 256 + threadIdx.x;
    if (i < N) {
        int r = rowptr[i] + blockoffs[i >> 8];
        rowptr[i] = r;
        next[i] = r;
    }
    if (i < total4) {
        float s = dinv[i >> 5];
        float4 v = ld4(&x[(long)i * 4]);
        v.x *= s; v.y *= s; v.z *= s; v.w *= s;
        st4(&xs[(long)i * 4], v);
    }
}

__global__ void fill_kernel(const int* __restrict__ ei, int E,
                            int* __restrict__ next, int* __restrict__ col) {
    int e = blockIdx.x * 256 + threadIdx.x;
    if (e < E) {
        int s = ei[e];
        int d = ei[E + e];
        int pos = atomicAdd(&next[d], 1);
        col[pos] = s;
    }
}

// All four weights: W[K,N] fp32 -> transposed TILED hi/lo planes (rows=n).
__global__ void wsplit_all(
    const float* __restrict__ W1, const float* __restrict__ W2,
    const float* __restrict__ Wd1, const float* __restrict__ Wd2,
    u16* __restrict__ w1h, u16* __restrict__ w1l, u16* __restrict__ w2h, u16* __restrict__ w2l,
    u16* __restrict__ wd1h, u16* __restrict__ wd1l, u16* __restrict__ wd2h, u16* __restrict__ wd2l) {
    int idx = blockIdx.x * 256 + threadIdx.x;
    const float* W; u16 *H, *L; int K, N, base;
    if (idx < 32768)      { W = W1;  H = w1h;  L = w1l;  K = 128; N = 256; base = idx; }
    else if (idx < 49152) { W = W2;  H = w2h;  L = w2l;  K = 256; N = 64;  base = idx - 32768; }
    else if (idx < 65536) { W = Wd1; H = wd1h; L = wd1l; K = 64;  N = 256; base = idx - 49152; }
    else if (idx < 98304) { W = Wd2; H = wd2h; L = wd2l; K = 256; N = 128; base = idx - 65536; }
    else return;
    int k = base / N, n = base % N;
    u16 h, l;
    split_bf16(W[base], h, l);
    long o = tix(n, k, K);
    H[o] = h;
    L[o] = l;
}

// ---------------- fused encoder: zs = (relu(xa@W1+b1) @ W2) * dinv ----------------
// Block = 32 rows (2 row-tiles), 4 waves. Stage A: out1[32,256] col-split
// across waves (64 cols each) -> LDS frag-tiled hi/lo (32 KB). Stage B:
// zs[32,64] col-split (16 cols/wave), A-frags from LDS.
__global__ __launch_bounds__(256) void enc_fused(
    const u16* __restrict__ xa_hi, const u16* __restrict__ xa_lo,
    const u16* __restrict__ w1h, const u16* __restrict__ w1l,
    const u16* __restrict__ w2h, const u16* __restrict__ w2l,
    const float* __restrict__ b1, const float* __restrict__ dinv,
    float* __restrict__ zs, int M) {
    __shared__ u16 o1[2][32 * 256];  // 32 KB

    const int tid = threadIdx.x;
    const int wid = tid >> 6, lane = tid & 63, quad = lane >> 4, lm = lane & 15;
    const int rt0 = blockIdx.x * 2;
    const int last_rt = (M >> 4) - 1;

    // ---- stage A: out1 = relu(xa @ W1 + b1), K=128 (KB=16, KC=4) ----
    f32x4 acc[2][4];
#pragma unroll
    for (int i = 0; i < 2; i++)
#pragma unroll
        for (int j = 0; j < 4; j++) acc[i][j] = (f32x4){0.f, 0.f, 0.f, 0.f};

#pragma unroll
    for (int kc = 0; kc < 4; kc++) {
        const int kb = kc * 4 + quad;
        bf16x8 ah[2], al[2], bh[4], bl[4];
#pragma unroll
        for (int i = 0; i < 2; i++) {
            int rt = rt0 + i; rt = rt <= last_rt ? rt : last_rt;
            long o = ((long)rt * 16 + kb) * 128 + lm * 8;
            ah[i] = *(const bf16x8*)&xa_hi[o];
            al[i] = *(const bf16x8*)&xa_lo[o];
        }
#pragma unroll
        for (int j = 0; j < 4; j++) {
            long o = ((long)(wid * 4 + j) * 16 + kb) * 128 + lm * 8;
            bh[j] = *(const bf16x8*)&w1h[o];
            bl[j] = *(const bf16x8*)&w1l[o];
        }
#pragma unroll
        for (int i = 0; i < 2; i++)
#pragma unroll
            for (int j = 0; j < 4; j++) { MFMA3(acc[i][j], ah[i], al[i], bh[j], bl[j]); }
    }

    // epilogue A -> LDS tiled (row in [0,32), k=coln in [0,256), KB=32)
#pragma unroll
    for (int i = 0; i < 2; i++)
#pragma unroll
        for (int j = 0; j < 4; j++) {
            int coln = wid * 64 + j * 16 + lm;
            float bi = b1[coln];
#pragma unroll
            for (int r = 0; r < 4; r++) {
                int row = i * 16 + quad * 4 + r;  // block-local
                float v = fmaxf(acc[i][j][r] + bi, 0.f);
                u16 h, l;
                split_bf16(v, h, l);
                int o = ((row >> 4) * 32 + (coln >> 3)) * 128 + ((row & 15) << 3) + (coln & 7);
                o1[0][o] = h;
                o1[1][o] = l;
            }
        }
    __syncthreads();

    // ---- stage B: zs = (out1 @ W2) * dinv, K=256 (KB=32, KC=8), 16 cols/wave ----
    f32x4 acc2[2];
    acc2[0] = (f32x4){0.f, 0.f, 0.f, 0.f};
    acc2[1] = (f32x4){0.f, 0.f, 0.f, 0.f};
#pragma unroll
    for (int kc = 0; kc < 8; kc++) {
        const int kb = kc * 4 + quad;
        bf16x8 ah[2], al[2], bh, bl;
#pragma unroll
        for (int i = 0; i < 2; i++) {
            int o = (i * 32 + kb) * 128 + lm * 8;
            ah[i] = *(const bf16x8*)&o1[0][o];
            al[i] = *(const bf16x8*)&o1[1][o];
        }
        {
            long o = ((long)wid * 32 + kb) * 128 + lm * 8;
            bh = *(const bf16x8*)&w2h[o];
            bl = *(const bf16x8*)&w2l[o];
        }
#pragma unroll
        for (int i = 0; i < 2; i++) { MFMA3(acc2[i], ah[i], al[i], bh, bl); }
    }
#pragma unroll
    for (int i = 0; i < 2; i++) {
        int coln = wid * 16 + lm;
#pragma unroll
        for (int r = 0; r < 4; r++) {
            int row = rt0 * 16 + i * 16 + quad * 4 + r;
            if (row < M) zs[(long)row * 64 + coln] = acc2[i][r] * dinv[row];
        }
    }
}

// ---------------- fused decoder: out = relu(z@Wd1+bd1)@Wd2 + bd2 ----------------
// Block = 32 rows, 4 waves. Stage A: d[32,256] (K=64) col-split 64/wave ->
// LDS frag-tiled (32 KB). Stage B: out[32,128] (K=256) col-split 32/wave.
__global__ __launch_bounds__(256) void dec_fused(
    const u16* __restrict__ z_hi, const u16* __restrict__ z_lo,
    const u16* __restrict__ wd1h, const u16* __restrict__ wd1l,
    const u16* __restrict__ wd2h, const u16* __restrict__ wd2l,
    const float* __restrict__ bd1, const float* __restrict__ bd2,
    float* __restrict__ out, int M) {
    __shared__ u16 dsm[2][32 * 256];  // 32 KB

    const int tid = threadIdx.x;
    const int wid = tid >> 6, lane = tid & 63, quad = lane >> 4, lm = lane & 15;
    const int rt0 = blockIdx.x * 2;
    const int last_rt = (M >> 4) - 1;

    // ---- stage A: d = relu(z @ Wd1 + bd1), K=64 (KB=8, KC=2) ----
    f32x4 acc[2][4];
#pragma unroll
    for (int i = 0; i < 2; i++)
#pragma unroll
        for (int j = 0; j < 4; j++) acc[i][j] = (f32x4){0.f, 0.f, 0.f, 0.f};

#pragma unroll
    for (int kc = 0; kc < 2; kc++) {
        const int kb = kc * 4 + quad;
        bf16x8 ah[2], al[2], bh[4], bl[4];
#pragma unroll
        for (int i = 0; i < 2; i++) {
            int rt = rt0 + i; rt = rt <= last_rt ? rt : last_rt;
            long o = ((long)rt * 8 + kb) * 128 + lm * 8;
            ah[i] = *(const bf16x8*)&z_hi[o];
            al[i] = *(const bf16x8*)&z_lo[o];
        }
#pragma unroll
        for (int j = 0; j < 4; j++) {
            long o = ((long)(wid * 4 + j) * 8 + kb) * 128 + lm * 8;
            bh[j] = *(const bf16x8*)&wd1h[o];
            bl[j] = *(const bf16x8*)&wd1l[o];
        }
#pragma unroll
        for (int i = 0; i < 2; i++)
#pragma unroll
            for (int j = 0; j < 4; j++) { MFMA3(acc[i][j], ah[i], al[i], bh[j], bl[j]); }
    }

    // epilogue A -> LDS tiled
#pragma unroll
    for (int i = 0; i < 2; i++)
#pragma unroll
        for (int j = 0; j < 4; j++) {
            int coln = wid * 64 + j * 16 + lm;
            float bi = bd1[coln];
#pragma unroll
            for (int r = 0; r < 4; r++) {
                int row = i * 16 + quad * 4 + r;
                float v = fmaxf(acc[i][j][r] + bi, 0.f);
                u16 h, l;
                split_bf16(v, h, l);
                int o = ((row >> 4) * 32 + (coln >> 3)) * 128 + ((row & 15) << 3) + (coln & 7);
                dsm[0][o] = h;
                dsm[1][o] = l;
            }
        }
    __syncthreads();

    // ---- stage B: out = d @ Wd2 + bd2, K=256 (KB=32, KC=8), 32 cols/wave ----
    f32x4 acc2[2][2];
#pragma unroll
    for (int i = 0; i < 2; i++)
#pragma unroll
        for (int j = 0; j < 2; j++) acc2[i][j] = (f32x4){0.f, 0.f, 0.f, 0.f};
#pragma unroll
    for (int kc = 0; kc < 8; kc++) {
        const int kb = kc * 4 + quad;
        bf16x8 ah[2], al[2], bh[2], bl[2];
#pragma unroll
        for (int i = 0; i < 2; i++) {
            int o = (i * 32 + kb) * 128 + lm * 8;
            ah[i] = *(const bf16x8*)&dsm[0][o];
            al[i] = *(const bf16x8*)&dsm[1][o];
        }
#pragma unroll
        for (int j = 0; j < 2; j++) {
            long o = ((long)(wid * 2 + j) * 32 + kb) * 128 + lm * 8;
            bh[j] = *(const bf16x8*)&wd2h[o];
            bl[j] = *(const bf16x8*)&wd2l[o];
        }
#pragma unroll
        for (int i = 0; i < 2; i++)
#pragma unroll
            for (int j = 0; j < 2; j++) { MFMA3(acc2[i][j], ah[i], al[i], bh[j], bl[j]); }
    }
#pragma unroll
    for (int i = 0; i < 2; i++)
#pragma unroll
        for (int j = 0; j < 2; j++) {
            int coln = wid * 32 + j * 16 + lm;
            float bi = bd2[coln];
#pragma unroll
            for (int r = 0; r < 4; r++) {
                int row = rt0 * 16 + i * 16 + quad * 4 + r;
                if (row < M) out[(long)row * 128 + coln] = acc2[i][j][r] + bi;
            }
        }
}

// ---------------- aggregation kernels ----------------

// AGGX: xa[i] = dinv[i]*(xs[i] + sum_in xs[s]); writes TILED hi/lo planes.
__global__ __launch_bounds__(256) void aggx_kernel(
    const float* __restrict__ xs, const int* __restrict__ rowptr, const int* __restrict__ col,
    const float* __restrict__ dinv, u16* __restrict__ xahi, u16* __restrict__ xalo, int N) {
    int wid = threadIdx.x >> 6;
    int lane = threadIdx.x & 63;
    int node = blockIdx.x * 4 + wid;
    if (node >= N) return;
    int slot = lane >> 5;
    int c = (lane & 31) * 4;

    float4 a0 = make_float4(0.f, 0.f, 0.f, 0.f);
    float4 a1 = a0, a2 = a0, a3 = a0;
    if (slot == 0) a0 = ld4(&xs[(long)node * 128 + c]);

    int beg = rowptr[node];
    int end = rowptr[node + 1];
    for (int cb = beg; cb < end; cb += 64) {
        int cnt = min(64, end - cb);
        int cv = (lane < cnt) ? col[cb + lane] : 0;
        int full = cnt >> 1;
        int trips = (cnt + 1) >> 1;
        int t = 0;
        for (; t + 4 <= full; t += 4) {
            int j = slot + 2 * t;
            int s0 = __shfl(cv, j);
            int s1 = __shfl(cv, j + 2);
            int s2 = __shfl(cv, j + 4);
            int s3 = __shfl(cv, j + 6);
            float4 v0 = ld4(&xs[(long)s0 * 128 + c]);
            float4 v1 = ld4(&xs[(long)s1 * 128 + c]);
            float4 v2 = ld4(&xs[(long)s2 * 128 + c]);
            float4 v3 = ld4(&xs[(long)s3 * 128 + c]);
            acc4(a0, v0); acc4(a1, v1); acc4(a2, v2); acc4(a3, v3);
        }
        for (; t < trips; t++) {
            int j = slot + 2 * t;
            bool p = j < cnt;
            int s = __shfl(cv, p ? j : 0);
            if (p) acc4(a0, ld4(&xs[(long)s * 128 + c]));
        }
    }
    acc4(a0, a1); acc4(a2, a3); acc4(a0, a2);
    a0.x += __shfl_xor(a0.x, 32);
    a0.y += __shfl_xor(a0.y, 32);
    a0.z += __shfl_xor(a0.z, 32);
    a0.w += __shfl_xor(a0.w, 32);
    if (slot == 0) {
        float di = dinv[node];
        a0.x *= di; a0.y *= di; a0.z *= di; a0.w *= di;
        ushort4 h, l;
        split_bf16(a0.x, h.x, l.x);
        split_bf16(a0.y, h.y, l.y);
        split_bf16(a0.z, h.z, l.z);
        split_bf16(a0.w, h.w, l.w);
        long o = tix(node, c, 128);
        *(ushort4*)&xahi[o] = h;
        *(ushort4*)&xalo[o] = l;
    }
}

// AGG2: z[i] = dinv[i]*(zs[i] + sum_in zs[s]) + b2; writes TILED hi/lo planes.
__global__ __launch_bounds__(256) void agg64_kernel(
    const float* __restrict__ zs, const int* __restrict__ rowptr, const int* __restrict__ col,
    const float* __restrict__ dinv, const float* __restrict__ bias,
    u16* __restrict__ zhi, u16* __restrict__ zlo, int N) {
    int wid = threadIdx.x >> 6;
    int lane = threadIdx.x & 63;
    int node = blockIdx.x * 4 + wid;
    if (node >= N) return;
    int slot = lane >> 4;
    int c = (lane & 15) * 4;

    float4 a0 = make_float4(0.f, 0.f, 0.f, 0.f);
    float4 a1 = a0;
    if (slot == 0) a0 = ld4(&zs[(long)node * 64 + c]);

    int beg = rowptr[node];
    int end = rowptr[node + 1];
    for (int cb = beg; cb < end; cb += 64) {
        int cnt = min(64, end - cb);
        int cv = (lane < cnt) ? col[cb + lane] : 0;
        int full = cnt >> 2;
        int trips = (cnt + 3) >> 2;
        int t = 0;
        for (; t + 2 <= full; t += 2) {
            int j = slot + 4 * t;
            int s0 = __shfl(cv, j);
            int s1 = __shfl(cv, j + 4);
            float4 v0 = ld4(&zs[(long)s0 * 64 + c]);
            float4 v1 = ld4(&zs[(long)s1 * 64 + c]);
            acc4(a0, v0); acc4(a1, v1);
        }
        for (; t < trips; t++) {
            int j = slot + 4 * t;
            bool p = j < cnt;
            int s = __shfl(cv, p ? j : 0);
            if (p) acc4(a0, ld4(&zs[(long)s * 64 + c]));
        }
    }
    acc4(a0, a1);
    a0.x += __shfl_xor(a0.x, 16); a0.x += __shfl_xor(a0.x, 32);
    a0.y += __shfl_xor(a0.y, 16); a0.y += __shfl_xor(a0.y, 32);
    a0.z += __shfl_xor(a0.z, 16); a0.z += __shfl_xor(a0.z, 32);
    a0.w += __shfl_xor(a0.w, 16); a0.w += __shfl_xor(a0.w, 32);
    if (slot == 0) {
        float di = dinv[node];
        float4 bi = ld4(&bias[c]);
        a0.x = a0.x * di + bi.x;
        a0.y = a0.y * di + bi.y;
        a0.z = a0.z * di + bi.z;
        a0.w = a0.w * di + bi.w;
        ushort4 h, l;
        split_bf16(a0.x, h.x, l.x);
        split_bf16(a0.y, h.y, l.y);
        split_bf16(a0.z, h.z, l.z);
        split_bf16(a0.w, h.w, l.w);
        long o = tix(node, c, 64);
        *(ushort4*)&zhi[o] = h;
        *(ushort4*)&zlo[o] = l;
    }
}

// ---------------- launch ----------------

extern "C" void kernel_launch(void* const* d_in, const int* in_sizes, int n_in,
                              void* d_out, int out_size, void* d_ws, size_t ws_size,
                              hipStream_t stream) {
    const float* x        = (const float*)d_in[0];
    const int* ei         = (const int*)d_in[1];   // int32 (harness integer convention)
    const float* W1       = (const float*)d_in[2];
    const float* b1       = (const float*)d_in[3];
    const float* W2       = (const float*)d_in[4];
    const float* b2       = (const float*)d_in[5];
    const float* Wd1      = (const float*)d_in[6];
    const float* bd1      = (const float*)d_in[7];
    const float* Wd2      = (const float*)d_in[8];
    const float* bd2      = (const float*)d_in[9];
    float* out            = (float*)d_out;

    const int N = in_sizes[0] / IN_CH;   // 50000 (multiple of 16)
    const int E = in_sizes[1] / 2;       // 800000

    char* p = (char*)d_ws;
    auto alloc = [&](size_t bytes) {
        char* r = p;
        p += (bytes + 255) & ~(size_t)255;
        return r;
    };
    int*   counts    = (int*)  alloc((size_t)(N + 1) * 4);
    int*   rowptr    = (int*)  alloc((size_t)(N + 1) * 4);
    int*   nxt       = (int*)  alloc((size_t)N * 4);
    int*   blocksums = (int*)  alloc(256 * 4);
    int*   blockoffs = (int*)  alloc(256 * 4);
    float* dinv      = (float*)alloc((size_t)N * 4);
    int*   col       = (int*)  alloc((size_t)E * 4);
    float* xs        = (float*)alloc((size_t)N * IN_CH * 4);
    u16*   xa_hi     = (u16*)  alloc((size_t)N * IN_CH * 2);
    u16*   xa_lo     = (u16*)  alloc((size_t)N * IN_CH * 2);
    float* zs        = (float*)alloc((size_t)N * LATENT * 4);
    u16*   z_hi      = (u16*)  alloc((size_t)N * LATENT * 2);
    u16*   z_lo      = (u16*)  alloc((size_t)N * LATENT * 2);
    u16*   w1t_hi    = (u16*)  alloc((size_t)IN_CH * HIDDEN * 2);
    u16*   w1t_lo    = (u16*)  alloc((size_t)IN_CH * HIDDEN * 2);
    u16*   w2t_hi    = (u16*)  alloc((size_t)HIDDEN * LATENT * 2);
    u16*   w2t_lo    = (u16*)  alloc((size_t)HIDDEN * LATENT * 2);
    u16*   wd1t_hi   = (u16*)  alloc((size_t)LATENT * HIDDEN * 2);
    u16*   wd1t_lo   = (u16*)  alloc((size_t)LATENT * HIDDEN * 2);
    u16*   wd2t_hi   = (u16*)  alloc((size_t)HIDDEN * IN_CH * 2);
    u16*   wd2t_lo   = (u16*)  alloc((size_t)HIDDEN * IN_CH * 2);

    const int nblk = (N + 255) / 256;
    const int total4 = N * (IN_CH / 4);

    hipMemsetAsync(counts, 0, (size_t)(N + 1) * 4, stream);
    hist_kernel<<<(E + 255) / 256, 256, 0, stream>>>(ei, E, counts);
    scan1_kernel<<<nblk, 256, 0, stream>>>(counts, rowptr, blocksums, dinv, N);
    scan2_kernel<<<1, 256, 0, stream>>>(blocksums, blockoffs, rowptr, nblk, N);
    scan3_prescale_kernel<<<(total4 + 255) / 256, 256, 0, stream>>>(
        rowptr, blockoffs, nxt, x, dinv, xs, N, total4);
    fill_kernel<<<(E + 255) / 256, 256, 0, stream>>>(ei, E, nxt, col);
    wsplit_all<<<384, 256, 0, stream>>>(W1, W2, Wd1, Wd2,
                                        w1t_hi, w1t_lo, w2t_hi, w2t_lo,
                                        wd1t_hi, wd1t_lo, wd2t_hi, wd2t_lo);

    // AGGX: xa = D^-1/2 A^ D^-1/2 X (tiled split out)
    aggx_kernel<<<(N + 3) / 4, 256, 0, stream>>>(xs, rowptr, col, dinv, xa_hi, xa_lo, N);

    const int fblk = (N + 31) / 32;  // 1563

    // enc_fused: zs = (relu(xa@W1+b1) @ W2) * dinv
    enc_fused<<<fblk, 256, 0, stream>>>(xa_hi, xa_lo, w1t_hi, w1t_lo,
                                        w2t_hi, w2t_lo, b1, dinv, zs, N);
    // AGG2: z = dinv*(sum zs) + b2 -> tiled split
    agg64_kernel<<<(N + 3) / 4, 256, 0, stream>>>(zs, rowptr, col, dinv, b2, z_hi, z_lo, N);
    // dec_fused: out = relu(z@Wd1+bd1) @ Wd2 + bd2
    dec_fused<<<fblk, 256, 0, stream>>>(z_hi, z_lo, wd1t_hi, wd1t_lo,
                                        wd2t_hi, wd2t_lo, bd1, bd2, out, N);
}